// Round 9
// baseline (118.054 us; speedup 1.0000x reference)
//
#include <hip/hip_runtime.h>

// AdditiveSelfAttentionLayer: B=4, N=1024, D=64, fp32
// out[b,i,d] = sum_j softmax_j( sum_d' tanh(x[b,i,d']+x[b,j,d']) ) * x[b,j,d]
//
// Identities:
//   tanh(s) = 1 - 2/(1+e^{2s});  e_j = sum_d tanh = 64 - 2*rsum
//   e^{2s} = E_i[d]*E_j[d],  E = exp2(C*x), C = 2*log2(e)  (E precomputed once)
//   PAIR MERGE: 1/(1+a) + 1/(1+b) = (2+p)/(1+p+q),  p=a+b, q=ab  (native v2f pk ops)
//   softmax shift 32: w_j = exp(e_j - 32) = exp2(32*log2e - C*rsum_j)
//
// Round 9: R7 (65us, verified) + T14 async-STAGE double buffer:
// issue tile t+1's global loads into REGISTERS before computing tile t
// (L2 latency ~300cyc hides under ~800cyc compute), ds_write after compute.
// Removes the global-load round trip from the per-tile critical path.

#define NB 4
#define NN 1024
#define ND 64
#define TJ 64             // j-rows per LDS tile (lane = local j)
#define TI 4              // i-rows per WG = waves per WG
#define NTILES (NN / TJ)  // 16

#if __has_builtin(__builtin_amdgcn_exp2f)
#define EXP2F(x) __builtin_amdgcn_exp2f(x)
#else
#define EXP2F(x) exp2f(x)
#endif
#if __has_builtin(__builtin_amdgcn_rcpf)
#define RCPF(x) __builtin_amdgcn_rcpf(x)
#else
#define RCPF(x) (1.0f / (x))
#endif

static constexpr float C_SCALE = 2.8853900817779268f;   // 2*log2(e)
static constexpr float K_SHIFT = 46.166241308446828f;   // 32*log2(e)

typedef float v2f __attribute__((ext_vector_type(2)));

#define PKFMA(a, b, c) __builtin_elementwise_fma((a), (b), (c))

__device__ __forceinline__ v2f vlo(float4 v) { v2f r; r.x = v.x; r.y = v.y; return r; }
__device__ __forceinline__ v2f vhi(float4 v) { v2f r; r.x = v.z; r.y = v.w; return r; }

// prep: E[i] = exp2(C * x[i]) for all B*N*D elements
__global__ __launch_bounds__(256) void prep_kernel(const float* __restrict__ x,
                                                   float* __restrict__ E) {
    int idx = blockIdx.x * 256 + threadIdx.x;
    float4 v = ((const float4*)x)[idx];
    float4 e;
    e.x = EXP2F(C_SCALE * v.x);
    e.y = EXP2F(C_SCALE * v.y);
    e.z = EXP2F(C_SCALE * v.z);
    e.w = EXP2F(C_SCALE * v.w);
    ((float4*)E)[idx] = e;
}

template <bool HAS_E>
__global__ __launch_bounds__(256, 3) void addattn_kernel(const float* __restrict__ x,
                                                         const float* __restrict__ E,
                                                         float* __restrict__ out) {
    __shared__ float E_lds[TJ * ND];   // 16 KB, XOR-swizzled at float4 grain
    __shared__ float x_lds[TJ * ND];   // 16 KB, same swizzle

    const int tid   = threadIdx.x;
    const int lane  = tid & 63;
    const int wave  = tid >> 6;
    const int wg    = blockIdx.x;
    const int b     = wg >> 8;                       // 256 WGs per batch
    const int ibase = (wg & 255) * TI;
    // wave-uniform i-row index (forced into SGPR so Ei loads become s_loads)
    const int i0    = __builtin_amdgcn_readfirstlane(ibase + wave);

    const float* xb  = x + (size_t)b * NN * ND;
    const float* Eb  = E + (size_t)b * NN * ND;
    const float* Eip = Eb + (size_t)i0 * ND;         // uniform pointer

    // ---- issue tile-0 global loads immediately (latency overlaps Ei setup) ----
    float4 px[4], pE[4];
    {
        const float4* srcx = (const float4*)xb;
        const float4* srcE = (const float4*)Eb;
        #pragma unroll
        for (int it = 0; it < 4; ++it) {
            int idx = it * 256 + tid;
            px[it] = srcx[idx];
            if (HAS_E) pE[it] = srcE[idx];
        }
    }

    // fallback (no workspace): Ei in VGPRs, computed once
    v2f ei2[32];
    if (!HAS_E) {
        #pragma unroll
        for (int c = 0; c < 16; ++c) {
            float4 xiq = *(const float4*)&xb[(size_t)i0 * ND + c * 4];  // uniform
            v2f lo, hi;
            lo.x = EXP2F(C_SCALE * xiq.x);
            lo.y = EXP2F(C_SCALE * xiq.y);
            hi.x = EXP2F(C_SCALE * xiq.z);
            hi.y = EXP2F(C_SCALE * xiq.w);
            ei2[2 * c] = lo;
            ei2[2 * c + 1] = hi;
        }
    }

    // ---- write tile 0 to LDS ----
    #pragma unroll
    for (int it = 0; it < 4; ++it) {
        int idx = it * 256 + tid;
        int j   = idx >> 4;         // 16 float4 per row
        int c   = idx & 15;
        int wof = j * ND + ((c ^ (j & 15)) << 2);
        *(float4*)&x_lds[wof] = px[it];
        float4 ev;
        if (HAS_E) {
            ev = pE[it];
        } else {
            ev.x = EXP2F(C_SCALE * px[it].x);
            ev.y = EXP2F(C_SCALE * px[it].y);
            ev.z = EXP2F(C_SCALE * px[it].z);
            ev.w = EXP2F(C_SCALE * px[it].w);
        }
        *(float4*)&E_lds[wof] = ev;
    }
    __syncthreads();

    v2f acc2[32];                       // out[i0] numerator, d-pairs, in-lane
    #pragma unroll
    for (int k = 0; k < 32; ++k) acc2[k] = (v2f){0.f, 0.f};
    float dn = 0.f;                     // per-lane denominator partial

    for (int t = 0; t < NTILES; ++t) {
        // ---- prefetch tile t+1 into registers (hides under this tile's compute) ----
        if (t + 1 < NTILES) {
            const float4* srcx = (const float4*)(xb + (size_t)(t + 1) * TJ * ND);
            const float4* srcE = (const float4*)(Eb + (size_t)(t + 1) * TJ * ND);
            #pragma unroll
            for (int it = 0; it < 4; ++it) {
                int idx = it * 256 + tid;
                px[it] = srcx[idx];
                if (HAS_E) pE[it] = srcE[idx];
            }
        }

        // ---- tanh phase: lane = local j; pair-merged packed rcp ----
        const int key = lane & 15;
        v2f rse = {0.f, 0.f}, rso = {0.f, 0.f};
        #pragma unroll
        for (int c = 0; c < 16; ++c) {
            float4 ejq = *(const float4*)&E_lds[lane * ND + ((c ^ key) << 2)];
            v2f eil, eih;
            if (HAS_E) {
                float4 eiq = *(const float4*)&Eip[c * 4];   // scalar (SGPR) load
                eil = vlo(eiq); eih = vhi(eiq);
            } else {
                eil = ei2[2 * c]; eih = ei2[2 * c + 1];
            }
            v2f a = eil * vlo(ejq);
            v2f q = eih * vhi(ejq);
            v2f p = a + q;
            v2f r = PKFMA(a, q, p + 1.0f);              // 1 + p + ab
            v2f tt; tt.x = RCPF(r.x); tt.y = RCPF(r.y);
            if (c & 1) rso = PKFMA(p + 2.0f, tt, rso);
            else       rse = PKFMA(p + 2.0f, tt, rse);
        }
        v2f rs = rse + rso;
        float w = EXP2F(fmaf(-C_SCALE, rs.x + rs.y, K_SHIFT)); // = exp(e_j - 32)
        dn += w;
        v2f w2; w2.x = w; w2.y = w;

        // ---- PV phase (in-register): acc[d] += w * x[j=lane][d] ----
        #pragma unroll
        for (int c = 0; c < 16; ++c) {
            float4 xq = *(const float4*)&x_lds[lane * ND + ((c ^ key) << 2)];
            acc2[2 * c]     = PKFMA(w2, vlo(xq), acc2[2 * c]);
            acc2[2 * c + 1] = PKFMA(w2, vhi(xq), acc2[2 * c + 1]);
        }

        // ---- publish prefetched tile ----
        if (t + 1 < NTILES) {
            __syncthreads();   // all waves done reading tile t
            #pragma unroll
            for (int it = 0; it < 4; ++it) {
                int idx = it * 256 + tid;
                int j   = idx >> 4;
                int c   = idx & 15;
                int wof = j * ND + ((c ^ (j & 15)) << 2);
                *(float4*)&x_lds[wof] = px[it];
                float4 ev;
                if (HAS_E) {
                    ev = pE[it];
                } else {
                    ev.x = EXP2F(C_SCALE * px[it].x);
                    ev.y = EXP2F(C_SCALE * px[it].y);
                    ev.z = EXP2F(C_SCALE * px[it].z);
                    ev.w = EXP2F(C_SCALE * px[it].w);
                }
                *(float4*)&E_lds[wof] = ev;
            }
            __syncthreads();   // publish tile t+1
        }
    }

    // ---- cross-lane transpose-reduction (round-1/7-verified butterfly) ----
    float* accf = (float*)acc2;
    #pragma unroll
    for (int s = 0; s < 6; ++s) {
        const int half = 32 >> s;
        const int sel  = (lane >> (5 - s)) & 1;
        #pragma unroll
        for (int k = 0; k < half; ++k) {
            float keep = sel ? accf[k + half] : accf[k];
            float send = sel ? accf[k] : accf[k + half];
            float recv = __shfl_xor(send, half, 64);
            accf[k] = keep + recv;
        }
    }
    #pragma unroll
    for (int s = 0; s < 6; ++s) dn += __shfl_xor(dn, 1 << s, 64);

    out[((size_t)b * NN + i0) * ND + lane] = accf[0] * RCPF(dn);
}

extern "C" void kernel_launch(void* const* d_in, const int* in_sizes, int n_in,
                              void* d_out, int out_size, void* d_ws, size_t ws_size,
                              hipStream_t stream) {
    const float* x = (const float*)d_in[0];
    float* out = (float*)d_out;
    const size_t e_bytes = (size_t)NB * NN * ND * sizeof(float);   // 1 MB

    dim3 grid(NB * (NN / TI));   // 1024 workgroups
    dim3 block(256);

    if (ws_size >= e_bytes) {
        float* E = (float*)d_ws;
        prep_kernel<<<dim3(NB * NN * ND / 4 / 256), dim3(256), 0, stream>>>(x, E);
        addattn_kernel<true><<<grid, block, 0, stream>>>(x, E, out);
    } else {
        addattn_kernel<false><<<grid, block, 0, stream>>>(x, (const float*)nullptr, out);
    }
}

// Round 10
// 67.978 us; speedup vs baseline: 1.7367x; 1.7367x over previous
//
#include <hip/hip_runtime.h>

// AdditiveSelfAttentionLayer: B=4, N=1024, D=64, fp32
// out[b,i,d] = sum_j softmax_j( sum_d' tanh(x[b,i,d']+x[b,j,d']) ) * x[b,j,d]
//
// Identities:
//   tanh(s) = 1 - 2/(1+e^{2s});  e_j = sum_d tanh = 64 - 2*rsum
//   e^{2s} = E_i[d]*E_j[d],  E = exp2(C*x), C = 2*log2(e)
//   PAIR MERGE: 1/(1+a) + 1/(1+b) = (2+p)/(1+p+q),  p=a+b, q=ab  (native v2f pk ops)
//   softmax shift 32: w_j = exp(e_j - 32) = exp2(32*log2e - C*rsum_j)
//
// Round 10: R9's publish-after-compute staging, de-spilled:
//  - prefetch x ONLY (16 VGPRs; R9's 32-reg px+pE prefetch spilled to scratch:
//    WRITE_SIZE 1MB->21MB was the smoking gun)
//  - E_lds computed from px at staging (16 exp2/thread/tile; trans has headroom)
//    -> E array never read from global inside the main kernel (FETCH halves)
//  - E workspace kept only for Ei scalar s_loads (SMEM pipe, 0 VGPR)
//  - launch_bounds(256,4): live set ~110 VGPR <= 128 -> 16 waves/CU

#define NB 4
#define NN 1024
#define ND 64
#define TJ 64             // j-rows per LDS tile (lane = local j)
#define TI 4              // i-rows per WG = waves per WG
#define NTILES (NN / TJ)  // 16

#if __has_builtin(__builtin_amdgcn_exp2f)
#define EXP2F(x) __builtin_amdgcn_exp2f(x)
#else
#define EXP2F(x) exp2f(x)
#endif
#if __has_builtin(__builtin_amdgcn_rcpf)
#define RCPF(x) __builtin_amdgcn_rcpf(x)
#else
#define RCPF(x) (1.0f / (x))
#endif

static constexpr float C_SCALE = 2.8853900817779268f;   // 2*log2(e)
static constexpr float K_SHIFT = 46.166241308446828f;   // 32*log2(e)

typedef float v2f __attribute__((ext_vector_type(2)));

#define PKFMA(a, b, c) __builtin_elementwise_fma((a), (b), (c))

__device__ __forceinline__ v2f vlo(float4 v) { v2f r; r.x = v.x; r.y = v.y; return r; }
__device__ __forceinline__ v2f vhi(float4 v) { v2f r; r.x = v.z; r.y = v.w; return r; }

// prep: E[i] = exp2(C * x[i]) — consumed only by the Ei scalar-load path
__global__ __launch_bounds__(256) void prep_kernel(const float* __restrict__ x,
                                                   float* __restrict__ E) {
    int idx = blockIdx.x * 256 + threadIdx.x;
    float4 v = ((const float4*)x)[idx];
    float4 e;
    e.x = EXP2F(C_SCALE * v.x);
    e.y = EXP2F(C_SCALE * v.y);
    e.z = EXP2F(C_SCALE * v.z);
    e.w = EXP2F(C_SCALE * v.w);
    ((float4*)E)[idx] = e;
}

template <bool HAS_E>
__global__ __launch_bounds__(256, 4) void addattn_kernel(const float* __restrict__ x,
                                                         const float* __restrict__ E,
                                                         float* __restrict__ out) {
    __shared__ float E_lds[TJ * ND];   // 16 KB, XOR-swizzled at float4 grain
    __shared__ float x_lds[TJ * ND];   // 16 KB, same swizzle

    const int tid   = threadIdx.x;
    const int lane  = tid & 63;
    const int wave  = tid >> 6;
    const int wg    = blockIdx.x;
    const int b     = wg >> 8;                       // 256 WGs per batch
    const int ibase = (wg & 255) * TI;
    // wave-uniform i-row index (forced into SGPR so Ei loads become s_loads)
    const int i0    = __builtin_amdgcn_readfirstlane(ibase + wave);

    const float* xb  = x + (size_t)b * NN * ND;
    const float* Eip = E + (size_t)b * NN * ND + (size_t)i0 * ND;  // uniform

    // ---- issue tile-0 x loads immediately ----
    float4 px[4];
    {
        const float4* srcx = (const float4*)xb;
        #pragma unroll
        for (int it = 0; it < 4; ++it) px[it] = srcx[it * 256 + tid];
    }

    // fallback (no workspace): Ei in VGPRs, computed once
    v2f ei2[32];
    if (!HAS_E) {
        #pragma unroll
        for (int c = 0; c < 16; ++c) {
            float4 xiq = *(const float4*)&xb[(size_t)i0 * ND + c * 4];  // uniform
            v2f lo, hi;
            lo.x = EXP2F(C_SCALE * xiq.x);
            lo.y = EXP2F(C_SCALE * xiq.y);
            hi.x = EXP2F(C_SCALE * xiq.z);
            hi.y = EXP2F(C_SCALE * xiq.w);
            ei2[2 * c] = lo;
            ei2[2 * c + 1] = hi;
        }
    }

    // ---- write tile 0 (E derived from px at staging) ----
    #pragma unroll
    for (int it = 0; it < 4; ++it) {
        int idx = it * 256 + tid;
        int j   = idx >> 4;         // 16 float4 per row
        int c   = idx & 15;
        int wof = j * ND + ((c ^ (j & 15)) << 2);
        *(float4*)&x_lds[wof] = px[it];
        float4 ev;
        ev.x = EXP2F(C_SCALE * px[it].x);
        ev.y = EXP2F(C_SCALE * px[it].y);
        ev.z = EXP2F(C_SCALE * px[it].z);
        ev.w = EXP2F(C_SCALE * px[it].w);
        *(float4*)&E_lds[wof] = ev;
    }
    __syncthreads();

    v2f acc2[32];                       // out[i0] numerator, d-pairs, in-lane
    #pragma unroll
    for (int k = 0; k < 32; ++k) acc2[k] = (v2f){0.f, 0.f};
    float dn = 0.f;                     // per-lane denominator partial

    for (int t = 0; t < NTILES; ++t) {
        // ---- prefetch tile t+1's x into registers (hides under compute) ----
        if (t + 1 < NTILES) {
            const float4* srcx = (const float4*)(xb + (size_t)(t + 1) * TJ * ND);
            #pragma unroll
            for (int it = 0; it < 4; ++it) px[it] = srcx[it * 256 + tid];
        }

        // ---- tanh phase: lane = local j; pair-merged packed rcp ----
        const int key = lane & 15;
        v2f rse = {0.f, 0.f}, rso = {0.f, 0.f};
        #pragma unroll
        for (int c = 0; c < 16; ++c) {
            float4 ejq = *(const float4*)&E_lds[lane * ND + ((c ^ key) << 2)];
            v2f eil, eih;
            if (HAS_E) {
                float4 eiq = *(const float4*)&Eip[c * 4];   // scalar (SGPR) load
                eil = vlo(eiq); eih = vhi(eiq);
            } else {
                eil = ei2[2 * c]; eih = ei2[2 * c + 1];
            }
            v2f a = eil * vlo(ejq);
            v2f q = eih * vhi(ejq);
            v2f p = a + q;
            v2f r = PKFMA(a, q, p + 1.0f);              // 1 + p + ab
            v2f tt; tt.x = RCPF(r.x); tt.y = RCPF(r.y);
            if (c & 1) rso = PKFMA(p + 2.0f, tt, rso);
            else       rse = PKFMA(p + 2.0f, tt, rse);
        }
        v2f rs = rse + rso;
        float w = EXP2F(fmaf(-C_SCALE, rs.x + rs.y, K_SHIFT)); // = exp(e_j - 32)
        dn += w;
        v2f w2; w2.x = w; w2.y = w;

        // ---- PV phase (in-register): acc[d] += w * x[j=lane][d] ----
        #pragma unroll
        for (int c = 0; c < 16; ++c) {
            float4 xq = *(const float4*)&x_lds[lane * ND + ((c ^ key) << 2)];
            acc2[2 * c]     = PKFMA(w2, vlo(xq), acc2[2 * c]);
            acc2[2 * c + 1] = PKFMA(w2, vhi(xq), acc2[2 * c + 1]);
        }

        // ---- publish prefetched tile (E derived at staging) ----
        if (t + 1 < NTILES) {
            __syncthreads();   // all waves done reading tile t
            #pragma unroll
            for (int it = 0; it < 4; ++it) {
                int idx = it * 256 + tid;
                int j   = idx >> 4;
                int c   = idx & 15;
                int wof = j * ND + ((c ^ (j & 15)) << 2);
                *(float4*)&x_lds[wof] = px[it];
                float4 ev;
                ev.x = EXP2F(C_SCALE * px[it].x);
                ev.y = EXP2F(C_SCALE * px[it].y);
                ev.z = EXP2F(C_SCALE * px[it].z);
                ev.w = EXP2F(C_SCALE * px[it].w);
                *(float4*)&E_lds[wof] = ev;
            }
            __syncthreads();   // publish tile t+1
        }
    }

    // ---- cross-lane transpose-reduction (round-1/7-verified butterfly) ----
    float* accf = (float*)acc2;
    #pragma unroll
    for (int s = 0; s < 6; ++s) {
        const int half = 32 >> s;
        const int sel  = (lane >> (5 - s)) & 1;
        #pragma unroll
        for (int k = 0; k < half; ++k) {
            float keep = sel ? accf[k + half] : accf[k];
            float send = sel ? accf[k] : accf[k + half];
            float recv = __shfl_xor(send, half, 64);
            accf[k] = keep + recv;
        }
    }
    #pragma unroll
    for (int s = 0; s < 6; ++s) dn += __shfl_xor(dn, 1 << s, 64);

    out[((size_t)b * NN + i0) * ND + lane] = accf[0] * RCPF(dn);
}

extern "C" void kernel_launch(void* const* d_in, const int* in_sizes, int n_in,
                              void* d_out, int out_size, void* d_ws, size_t ws_size,
                              hipStream_t stream) {
    const float* x = (const float*)d_in[0];
    float* out = (float*)d_out;
    const size_t e_bytes = (size_t)NB * NN * ND * sizeof(float);   // 1 MB

    dim3 grid(NB * (NN / TI));   // 1024 workgroups
    dim3 block(256);

    if (ws_size >= e_bytes) {
        float* E = (float*)d_ws;
        prep_kernel<<<dim3(NB * NN * ND / 4 / 256), dim3(256), 0, stream>>>(x, E);
        addattn_kernel<true><<<grid, block, 0, stream>>>(x, E, out);
    } else {
        addattn_kernel<false><<<grid, block, 0, stream>>>(x, (const float*)nullptr, out);
    }
}